// Round 3
// baseline (813.031 us; speedup 1.0000x reference)
//
#include <hip/hip_runtime.h>
#include <math.h>

#define DD 64
#define NN 512
#define LL 1024
#define EPSF 1e-5f

// ---------------------------------------------------------------------------
// Kernel A: block per l; thread t owns rows n = t and n = 256+t, fully in
// registers (16B/lane strided loads, full-line use within wave). LN, k/v
// projections (Wk/Wv = 4KB -> scalar-cache resident s_loads), xbar via
// in-register recursive-halving butterfly (compile-time indices only).
// ---------------------------------------------------------------------------
__global__ __launch_bounds__(256, 3) void kA(
    const float* __restrict__ msa, const float* __restrict__ lnw, const float* __restrict__ lnb,
    const float* __restrict__ Wk, const float* __restrict__ Wv,
    float* __restrict__ kb, float* __restrict__ vb, float* __restrict__ xbar)
{
  __shared__ float red[4 * DD];   // per-wave partial xbar
  const int l = blockIdx.x;
  const int t = threadIdx.x;
  const int lane = t & 63;
  const int w = t >> 6;

  float xacc[DD];
#pragma unroll
  for (int d = 0; d < DD; ++d) xacc[d] = 0.f;

#pragma unroll 1
  for (int c = 0; c < 2; ++c) {
    const int n = c * 256 + t;
    const float4* rp = (const float4*)(msa + ((size_t)n * LL + l) * DD);
    float4 r4[16];
#pragma unroll
    for (int i = 0; i < 16; ++i) r4[i] = rp[i];

    float s = 0.f, s2 = 0.f;
#pragma unroll
    for (int i = 0; i < 16; ++i) {
      const float4 f = r4[i];
      s += (f.x + f.y) + (f.z + f.w);
      s2 = fmaf(f.x, f.x, s2); s2 = fmaf(f.y, f.y, s2);
      s2 = fmaf(f.z, f.z, s2); s2 = fmaf(f.w, f.w, s2);
    }
    const float mu = s * (1.f / DD);
    const float rs = rsqrtf(fmaf(-mu, mu, s2 * (1.f / DD)) + EPSF);

    float ka[8], va[8];
#pragma unroll
    for (int j = 0; j < 8; ++j) { ka[j] = 0.f; va[j] = 0.f; }

#pragma unroll
    for (int i = 0; i < 16; ++i) {
      const float4 f = r4[i];
#define KA_STEP(comp, c4)                                            \
      {                                                              \
        const int d = 4 * i + (c4);                                  \
        const float xn = fmaf((f.comp - mu) * rs, lnw[d], lnb[d]);   \
        xacc[d] += xn;                                               \
        _Pragma("unroll")                                            \
        for (int j = 0; j < 8; ++j) {                                \
          ka[j] = fmaf(xn, Wk[d * 8 + j], ka[j]);                    \
          va[j] = fmaf(xn, Wv[d * 8 + j], va[j]);                    \
        }                                                            \
      }
      KA_STEP(x, 0) KA_STEP(y, 1) KA_STEP(z, 2) KA_STEP(w, 3)
#undef KA_STEP
    }

    float4* kp = (float4*)(kb + ((size_t)l * NN + n) * 8);
    float4* vp = (float4*)(vb + ((size_t)l * NN + n) * 8);
    kp[0] = make_float4(ka[0], ka[1], ka[2], ka[3]);
    kp[1] = make_float4(ka[4], ka[5], ka[6], ka[7]);
    vp[0] = make_float4(va[0], va[1], va[2], va[3]);
    vp[1] = make_float4(va[4], va[5], va[6], va[7]);
  }

  // recursive-halving butterfly: after log2(64) steps lane j holds sum over
  // all 64 lanes of xacc[j]. All register indices compile-time.
#pragma unroll
  for (int half = 32; half >= 1; half >>= 1) {
    const bool hi = (lane & half) != 0;
#pragma unroll
    for (int k = 0; k < half; ++k) {
      const float keep = hi ? xacc[k + half] : xacc[k];
      const float send = hi ? xacc[k]        : xacc[k + half];
      xacc[k] = keep + __shfl_xor(send, half);
    }
  }
  red[w * DD + lane] = xacc[0];
  __syncthreads();
  if (t < DD)
    xbar[(size_t)l * DD + t] =
        (red[t] + red[DD + t] + red[2 * DD + t] + red[3 * DD + t]) * (1.f / NN);
}

// ---------------------------------------------------------------------------
// Kernel B: per l: q = xbar@Wq (scaled), scores over n, softmax, o = attn@v.
// grid = L blocks, 512 threads = 8 waves; wave h owns head h. (unchanged)
// ---------------------------------------------------------------------------
__global__ __launch_bounds__(512) void kB(
    const float* __restrict__ kb, const float* __restrict__ vb,
    const float* __restrict__ xbar, const float* __restrict__ Wq,
    float* __restrict__ ob)
{
  __shared__ float qs[DD];
  __shared__ float ks[NN * 9];
  __shared__ float vs[NN * 9];
  const int l = blockIdx.x;
  const int t = threadIdx.x;
  const int h = t >> 6;
  const int lane = t & 63;

  const float* kl = kb + (size_t)l * NN * 8;
  const float* vl = vb + (size_t)l * NN * 8;
#pragma unroll
  for (int i = 0; i < 8; ++i) {
    const int idx = i * 512 + t;
    const int n = idx >> 3, j = idx & 7;
    ks[n*9 + j] = kl[idx];
    vs[n*9 + j] = vl[idx];
  }
  if (t < DD) {
    float acc = 0.f;
    for (int d = 0; d < DD; ++d) acc = fmaf(xbar[l*DD + d], Wq[d*DD + t], acc);
    qs[t] = acc * 0.35355339059327373f;
  }
  __syncthreads();

  float sc[8];
  float m = -1e30f;
#pragma unroll
  for (int i = 0; i < 8; ++i) {
    const int n = i * 64 + lane;
    float s = 0.f;
#pragma unroll
    for (int d = 0; d < 8; ++d) s = fmaf(qs[h*8 + d], ks[n*9 + d], s);
    sc[i] = s;
    m = fmaxf(m, s);
  }
#pragma unroll
  for (int off = 32; off; off >>= 1) m = fmaxf(m, __shfl_xor(m, off));
  float ssum = 0.f;
#pragma unroll
  for (int i = 0; i < 8; ++i) { sc[i] = __expf(sc[i] - m); ssum += sc[i]; }
#pragma unroll
  for (int off = 32; off; off >>= 1) ssum += __shfl_xor(ssum, off);
  const float inv = 1.f / ssum;

  float oacc[8];
#pragma unroll
  for (int d = 0; d < 8; ++d) oacc[d] = 0.f;
#pragma unroll
  for (int i = 0; i < 8; ++i) {
    const int n = i * 64 + lane;
#pragma unroll
    for (int d = 0; d < 8; ++d) oacc[d] = fmaf(sc[i], vs[n*9 + d], oacc[d]);
  }
#pragma unroll
  for (int d = 0; d < 8; ++d) {
#pragma unroll
    for (int off = 32; off; off >>= 1) oacc[d] += __shfl_xor(oacc[d], off);
  }
  if (lane == 0) {
    float4* op = (float4*)(ob + (size_t)l * DD + h * 8);
    op[0] = make_float4(oacc[0]*inv, oacc[1]*inv, oacc[2]*inv, oacc[3]*inv);
    op[1] = make_float4(oacc[4]*inv, oacc[5]*inv, oacc[6]*inv, oacc[7]*inv);
  }
}

// ---------------------------------------------------------------------------
// Kernel C: thread-per-row, fully register-resident (no LDS, no barriers).
// row (16 float4) -> LN -> acc[64] = xn@Wg (s_load weights) -> sigmoid*o
// -> oa[64] = t@Wout + bout -> store. launch_bounds(256,3): cap 170 VGPR,
// ~150 needed -> no scratch.
// ---------------------------------------------------------------------------
__global__ __launch_bounds__(256, 3) void kC(
    const float* __restrict__ msa, const float* __restrict__ lnw, const float* __restrict__ lnb,
    const float* __restrict__ Wg, const float* __restrict__ bg,
    const float* __restrict__ ob, const float* __restrict__ Wout, const float* __restrict__ bout,
    float* __restrict__ out)
{
  const int t = threadIdx.x;
  const size_t row = (size_t)blockIdx.x * 256 + t;
  const int l = (int)(row & (LL - 1));

  const float4* rp = (const float4*)(msa + row * DD);
  float4 r4[16];
#pragma unroll
  for (int i = 0; i < 16; ++i) r4[i] = rp[i];

  float s = 0.f, s2 = 0.f;
#pragma unroll
  for (int i = 0; i < 16; ++i) {
    const float4 f = r4[i];
    s += (f.x + f.y) + (f.z + f.w);
    s2 = fmaf(f.x, f.x, s2); s2 = fmaf(f.y, f.y, s2);
    s2 = fmaf(f.z, f.z, s2); s2 = fmaf(f.w, f.w, s2);
  }
  const float mu = s * (1.f / DD);
  const float rs = rsqrtf(fmaf(-mu, mu, s2 * (1.f / DD)) + EPSF);

  // mv1: acc[j] = sum_d xn_d * Wg[d][j]
  float acc[DD];
#pragma unroll
  for (int j = 0; j < DD; ++j) acc[j] = 0.f;
#pragma unroll
  for (int i = 0; i < 16; ++i) {
    const float4 f = r4[i];
#define KC_STEP(comp, c4)                                            \
    {                                                                \
      const int d = 4 * i + (c4);                                    \
      const float xn = fmaf((f.comp - mu) * rs, lnw[d], lnb[d]);     \
      _Pragma("unroll")                                              \
      for (int j = 0; j < DD; ++j)                                   \
        acc[j] = fmaf(xn, Wg[d * DD + j], acc[j]);                   \
    }
    KC_STEP(x, 0) KC_STEP(y, 1) KC_STEP(z, 2) KC_STEP(w, 3)
#undef KC_STEP
  }

  // t_j = sigmoid(acc_j + bg_j) * o[l][j]  (in place)
  const float4* op4 = (const float4*)(ob + (size_t)l * DD);
#pragma unroll
  for (int q = 0; q < 16; ++q) {
    const float4 ov = op4[q];
    acc[4*q+0] = ov.x / (1.f + __expf(-(acc[4*q+0] + bg[4*q+0])));
    acc[4*q+1] = ov.y / (1.f + __expf(-(acc[4*q+1] + bg[4*q+1])));
    acc[4*q+2] = ov.z / (1.f + __expf(-(acc[4*q+2] + bg[4*q+2])));
    acc[4*q+3] = ov.w / (1.f + __expf(-(acc[4*q+3] + bg[4*q+3])));
  }

  // mv2: oa[j] = bout[j] + sum_d t_d * Wout[d][j]  (oa reuses r4's registers)
  float oa[DD];
#pragma unroll
  for (int j = 0; j < DD; ++j) oa[j] = bout[j];
#pragma unroll
  for (int d = 0; d < DD; ++d) {
    const float td = acc[d];
#pragma unroll
    for (int j = 0; j < DD; ++j)
      oa[j] = fmaf(td, Wout[d * DD + j], oa[j]);
  }

  float4* outp = (float4*)(out + row * DD);
#pragma unroll
  for (int q = 0; q < 16; ++q)
    outp[q] = make_float4(oa[4*q+0], oa[4*q+1], oa[4*q+2], oa[4*q+3]);
}

// ---------------------------------------------------------------------------
extern "C" void kernel_launch(void* const* d_in, const int* in_sizes, int n_in,
                              void* d_out, int out_size, void* d_ws, size_t ws_size,
                              hipStream_t stream)
{
  const float* msa  = (const float*)d_in[0];
  const float* lnw  = (const float*)d_in[1];
  const float* lnb  = (const float*)d_in[2];
  const float* Wq   = (const float*)d_in[3];
  const float* Wk   = (const float*)d_in[4];
  const float* Wv   = (const float*)d_in[5];
  const float* Wg   = (const float*)d_in[6];
  const float* bg   = (const float*)d_in[7];
  const float* Wout = (const float*)d_in[8];
  const float* bout = (const float*)d_in[9];
  float* out = (float*)d_out;

  float* kb   = (float*)d_ws;                       // (L, N, 8) 16 MB
  float* vb   = kb + (size_t)LL * NN * 8;           // (L, N, 8) 16 MB
  float* xbar = vb + (size_t)LL * NN * 8;           // (L, 64)  256 KB
  float* ob   = xbar + (size_t)LL * DD;             // (L, 64)  256 KB

  kA<<<LL, 256, 0, stream>>>(msa, lnw, lnb, Wk, Wv, kb, vb, xbar);
  kB<<<LL, 512, 0, stream>>>(kb, vb, xbar, Wq, ob);
  kC<<<(NN * LL) / 256, 256, 0, stream>>>(msa, lnw, lnb, Wg, bg, ob, Wout, bout, out);
}

// Round 4
// 243.689 us; speedup vs baseline: 3.3364x; 3.3364x over previous
//
#include <hip/hip_runtime.h>
#include <math.h>

#define DD 64
#define NN 512
#define LL 1024
#define EPSF 1e-5f

typedef short short8 __attribute__((ext_vector_type(8)));
typedef float f32x4 __attribute__((ext_vector_type(4)));

// round-to-nearest-even bf16 (bits in low 16)
static __device__ __forceinline__ unsigned bf16_rne(float f) {
  unsigned u = __float_as_uint(f);
  return (u + 0x7FFFu + ((u >> 16) & 1u)) >> 16;
}
// the rne-rounded bf16 value, as fp32
static __device__ __forceinline__ float bf16_hi_f(float f) {
  unsigned u = __float_as_uint(f);
  return __uint_as_float((u + 0x7FFFu + ((u >> 16) & 1u)) & 0xFFFF0000u);
}

// ---------------------------------------------------------------------------
// Kernel W: pack Wg/Wout into MFMA B-fragment order, split bf16 hi/lo.
// Bpk dword index: (((mv*2 + h)*8 + ct*2 + kt)*64 + lane)*4 + e2
// element: col = ct*16 + (lane&15); k = kt*32 + (lane>>4)*8 + e2*2 + {0,1}
// dword = bf16(k) | bf16(k+1)<<16   (element order matches short8 memory order)
// ---------------------------------------------------------------------------
__global__ __launch_bounds__(256) void kW(const float* __restrict__ Wg,
                                          const float* __restrict__ Wout,
                                          unsigned* __restrict__ Bpk)
{
  const int idx = blockIdx.x * 256 + threadIdx.x;   // 0..8191
  const int e2   = idx & 3;
  const int lane = (idx >> 2) & 63;
  const int ctkt = (idx >> 8) & 7;
  const int h    = (idx >> 11) & 1;
  const int mv   = (idx >> 12) & 1;
  const int col  = ((ctkt >> 1) << 4) | (lane & 15);
  const int k0   = ((ctkt & 1) << 5) + ((lane >> 4) << 3) + (e2 << 1);
  const float* W = mv ? Wout : Wg;
  const float w0 = W[k0 * DD + col];
  const float w1 = W[(k0 + 1) * DD + col];
  unsigned b0, b1;
  if (h == 0) { b0 = bf16_rne(w0); b1 = bf16_rne(w1); }
  else        { b0 = bf16_rne(w0 - bf16_hi_f(w0)); b1 = bf16_rne(w1 - bf16_hi_f(w1)); }
  Bpk[idx] = b0 | (b1 << 16);
}

// ---------------------------------------------------------------------------
// Kernel A: unchanged from R3 (known-working). Block per l; thread owns rows
// n=t, n=256+t in registers; LN + k/v proj; xbar via register butterfly.
// ---------------------------------------------------------------------------
__global__ __launch_bounds__(256, 3) void kA(
    const float* __restrict__ msa, const float* __restrict__ lnw, const float* __restrict__ lnb,
    const float* __restrict__ Wk, const float* __restrict__ Wv,
    float* __restrict__ kb, float* __restrict__ vb, float* __restrict__ xbar)
{
  __shared__ float red[4 * DD];
  const int l = blockIdx.x;
  const int t = threadIdx.x;
  const int lane = t & 63;
  const int w = t >> 6;

  float xacc[DD];
#pragma unroll
  for (int d = 0; d < DD; ++d) xacc[d] = 0.f;

#pragma unroll 1
  for (int c = 0; c < 2; ++c) {
    const int n = c * 256 + t;
    const float4* rp = (const float4*)(msa + ((size_t)n * LL + l) * DD);
    float4 r4[16];
#pragma unroll
    for (int i = 0; i < 16; ++i) r4[i] = rp[i];

    float s = 0.f, s2 = 0.f;
#pragma unroll
    for (int i = 0; i < 16; ++i) {
      const float4 f = r4[i];
      s += (f.x + f.y) + (f.z + f.w);
      s2 = fmaf(f.x, f.x, s2); s2 = fmaf(f.y, f.y, s2);
      s2 = fmaf(f.z, f.z, s2); s2 = fmaf(f.w, f.w, s2);
    }
    const float mu = s * (1.f / DD);
    const float rs = rsqrtf(fmaf(-mu, mu, s2 * (1.f / DD)) + EPSF);

    float ka[8], va[8];
#pragma unroll
    for (int j = 0; j < 8; ++j) { ka[j] = 0.f; va[j] = 0.f; }

#pragma unroll
    for (int i = 0; i < 16; ++i) {
      const float4 f = r4[i];
#define KA_STEP(comp, c4)                                            \
      {                                                              \
        const int d = 4 * i + (c4);                                  \
        const float xn = fmaf((f.comp - mu) * rs, lnw[d], lnb[d]);   \
        xacc[d] += xn;                                               \
        _Pragma("unroll")                                            \
        for (int j = 0; j < 8; ++j) {                                \
          ka[j] = fmaf(xn, Wk[d * 8 + j], ka[j]);                    \
          va[j] = fmaf(xn, Wv[d * 8 + j], va[j]);                    \
        }                                                            \
      }
      KA_STEP(x, 0) KA_STEP(y, 1) KA_STEP(z, 2) KA_STEP(w, 3)
#undef KA_STEP
    }

    float4* kp = (float4*)(kb + ((size_t)l * NN + n) * 8);
    float4* vp = (float4*)(vb + ((size_t)l * NN + n) * 8);
    kp[0] = make_float4(ka[0], ka[1], ka[2], ka[3]);
    kp[1] = make_float4(ka[4], ka[5], ka[6], ka[7]);
    vp[0] = make_float4(va[0], va[1], va[2], va[3]);
    vp[1] = make_float4(va[4], va[5], va[6], va[7]);
  }

#pragma unroll
  for (int half = 32; half >= 1; half >>= 1) {
    const bool hi = (lane & half) != 0;
#pragma unroll
    for (int k = 0; k < half; ++k) {
      const float keep = hi ? xacc[k + half] : xacc[k];
      const float send = hi ? xacc[k]        : xacc[k + half];
      xacc[k] = keep + __shfl_xor(send, half);
    }
  }
  red[w * DD + lane] = xacc[0];
  __syncthreads();
  if (t < DD)
    xbar[(size_t)l * DD + t] =
        (red[t] + red[DD + t] + red[2 * DD + t] + red[3 * DD + t]) * (1.f / NN);
}

// ---------------------------------------------------------------------------
// Kernel B: unchanged from R3.
// ---------------------------------------------------------------------------
__global__ __launch_bounds__(512) void kB(
    const float* __restrict__ kb, const float* __restrict__ vb,
    const float* __restrict__ xbar, const float* __restrict__ Wq,
    float* __restrict__ ob)
{
  __shared__ float qs[DD];
  __shared__ float ks[NN * 9];
  __shared__ float vs[NN * 9];
  const int l = blockIdx.x;
  const int t = threadIdx.x;
  const int h = t >> 6;
  const int lane = t & 63;

  const float* kl = kb + (size_t)l * NN * 8;
  const float* vl = vb + (size_t)l * NN * 8;
#pragma unroll
  for (int i = 0; i < 8; ++i) {
    const int idx = i * 512 + t;
    const int n = idx >> 3, j = idx & 7;
    ks[n*9 + j] = kl[idx];
    vs[n*9 + j] = vl[idx];
  }
  if (t < DD) {
    float acc = 0.f;
    for (int d = 0; d < DD; ++d) acc = fmaf(xbar[l*DD + d], Wq[d*DD + t], acc);
    qs[t] = acc * 0.35355339059327373f;
  }
  __syncthreads();

  float sc[8];
  float m = -1e30f;
#pragma unroll
  for (int i = 0; i < 8; ++i) {
    const int n = i * 64 + lane;
    float s = 0.f;
#pragma unroll
    for (int d = 0; d < 8; ++d) s = fmaf(qs[h*8 + d], ks[n*9 + d], s);
    sc[i] = s;
    m = fmaxf(m, s);
  }
#pragma unroll
  for (int off = 32; off; off >>= 1) m = fmaxf(m, __shfl_xor(m, off));
  float ssum = 0.f;
#pragma unroll
  for (int i = 0; i < 8; ++i) { sc[i] = __expf(sc[i] - m); ssum += sc[i]; }
#pragma unroll
  for (int off = 32; off; off >>= 1) ssum += __shfl_xor(ssum, off);
  const float inv = 1.f / ssum;

  float oacc[8];
#pragma unroll
  for (int d = 0; d < 8; ++d) oacc[d] = 0.f;
#pragma unroll
  for (int i = 0; i < 8; ++i) {
    const int n = i * 64 + lane;
#pragma unroll
    for (int d = 0; d < 8; ++d) oacc[d] = fmaf(sc[i], vs[n*9 + d], oacc[d]);
  }
#pragma unroll
  for (int d = 0; d < 8; ++d) {
#pragma unroll
    for (int off = 32; off; off >>= 1) oacc[d] += __shfl_xor(oacc[d], off);
  }
  if (lane == 0) {
    float4* op = (float4*)(ob + (size_t)l * DD + h * 8);
    op[0] = make_float4(oacc[0]*inv, oacc[1]*inv, oacc[2]*inv, oacc[3]*inv);
    op[1] = make_float4(oacc[4]*inv, oacc[5]*inv, oacc[6]*inv, oacc[7]*inv);
  }
}

// ---------------------------------------------------------------------------
// Kernel C (MFMA, split-bf16 3-term): 128 rows/block, 256 thr = 4 waves.
// Wave w owns local rows [32w, 32w+32) x all 64 cols (acc = 8 x f32x4).
// LDS: Bl 16KB (one matvec's W-pack) + XH/XL 2x18KB (xn / t split-bf16,
// pad 72). 53 KB -> 3 blocks/CU.
// A-frag: lane holds row=(lane&15), k=8*(lane>>4)+e (e=0..7, short8).
// C/D (HW-verified): reg j -> row=(lane>>4)*4+j, col=lane&15.
// ---------------------------------------------------------------------------
__global__ __launch_bounds__(256, 4) void kC(
    const float* __restrict__ msa, const float* __restrict__ lnw, const float* __restrict__ lnb,
    const unsigned* __restrict__ Bpk, const float* __restrict__ bg,
    const float* __restrict__ ob, const float* __restrict__ bout,
    float* __restrict__ out)
{
  __shared__ unsigned Bl[4096];            // 16 KB
  __shared__ unsigned short XH[128 * 72];  // 18 KB
  __shared__ unsigned short XL[128 * 72];  // 18 KB
  const int t = threadIdx.x;
  const int lane = t & 63;
  const int w = t >> 6;
  const int rbase = 32 * w;
  const size_t R0 = (size_t)blockIdx.x * 128;

  // stage Wg pack
#pragma unroll
  for (int i = 0; i < 16; ++i) Bl[i * 256 + t] = Bpk[i * 256 + t];

  // xn phase: threads 0..127 each own one row
  if (t < 128) {
    const float4* rp = (const float4*)(msa + (R0 + t) * DD);
    float4 r4[16];
#pragma unroll
    for (int i = 0; i < 16; ++i) r4[i] = rp[i];
    float s = 0.f, s2 = 0.f;
#pragma unroll
    for (int i = 0; i < 16; ++i) {
      const float4 f = r4[i];
      s += (f.x + f.y) + (f.z + f.w);
      s2 = fmaf(f.x, f.x, s2); s2 = fmaf(f.y, f.y, s2);
      s2 = fmaf(f.z, f.z, s2); s2 = fmaf(f.w, f.w, s2);
    }
    const float mu = s * (1.f / DD);
    const float rs = rsqrtf(fmaf(-mu, mu, s2 * (1.f / DD)) + EPSF);
    const float aa = rs, bb = -mu * rs;
#pragma unroll
    for (int i = 0; i < 16; ++i) {
      const float xs0 = r4[i].x, xs1 = r4[i].y, xs2 = r4[i].z, xs3 = r4[i].w;
      unsigned hh[4], ll[4];
#define XN_SPLIT(c, xv)                                               \
      {                                                               \
        const int d = 4 * i + (c);                                    \
        const float xn = fmaf(fmaf((xv), aa, bb), lnw[d], lnb[d]);    \
        const float hf = bf16_hi_f(xn);                               \
        hh[c] = bf16_rne(xn);                                         \
        ll[c] = bf16_rne(xn - hf);                                    \
      }
      XN_SPLIT(0, xs0) XN_SPLIT(1, xs1) XN_SPLIT(2, xs2) XN_SPLIT(3, xs3)
#undef XN_SPLIT
      *(uint2*)&XH[t * 72 + 4 * i] = make_uint2(hh[0] | (hh[1] << 16), hh[2] | (hh[3] << 16));
      *(uint2*)&XL[t * 72 + 4 * i] = make_uint2(ll[0] | (ll[1] << 16), ll[2] | (ll[3] << 16));
    }
  }
  __syncthreads();

  // 48-MFMA matvec over this wave's 32 rows (split-bf16 3-term)
  auto run_mv = [&](f32x4 acc[2][4]) {
#pragma unroll
    for (int rt = 0; rt < 2; ++rt) {
      const int row = rbase + rt * 16 + (lane & 15);
      const int kg = (lane >> 4) * 8;
      const short8 ah0 = *(const short8*)&XH[row * 72 + kg];
      const short8 ah1 = *(const short8*)&XH[row * 72 + 32 + kg];
      const short8 al0 = *(const short8*)&XL[row * 72 + kg];
      const short8 al1 = *(const short8*)&XL[row * 72 + 32 + kg];
#pragma unroll
      for (int ct = 0; ct < 4; ++ct) {
        const short8 bh0 = *(const short8*)&Bl[((0 * 8 + ct * 2 + 0) * 64 + lane) * 4];
        const short8 bh1 = *(const short8*)&Bl[((0 * 8 + ct * 2 + 1) * 64 + lane) * 4];
        const short8 bl0 = *(const short8*)&Bl[((1 * 8 + ct * 2 + 0) * 64 + lane) * 4];
        const short8 bl1 = *(const short8*)&Bl[((1 * 8 + ct * 2 + 1) * 64 + lane) * 4];
        f32x4 c = acc[rt][ct];
        c = __builtin_amdgcn_mfma_f32_16x16x32_bf16(ah0, bh0, c, 0, 0, 0);
        c = __builtin_amdgcn_mfma_f32_16x16x32_bf16(ah1, bh1, c, 0, 0, 0);
        c = __builtin_amdgcn_mfma_f32_16x16x32_bf16(ah0, bl0, c, 0, 0, 0);
        c = __builtin_amdgcn_mfma_f32_16x16x32_bf16(ah1, bl1, c, 0, 0, 0);
        c = __builtin_amdgcn_mfma_f32_16x16x32_bf16(al0, bh0, c, 0, 0, 0);
        c = __builtin_amdgcn_mfma_f32_16x16x32_bf16(al1, bh1, c, 0, 0, 0);
        acc[rt][ct] = c;
      }
    }
  };

  f32x4 acc[2][4];
#pragma unroll
  for (int rt = 0; rt < 2; ++rt)
#pragma unroll
    for (int ct = 0; ct < 4; ++ct) acc[rt][ct] = f32x4{0.f, 0.f, 0.f, 0.f};
  run_mv(acc);   // mv1: gate pre-activation

  // sigmoid * o -> t, split-bf16 back into XH/XL (wave-private rows)
#pragma unroll
  for (int rt = 0; rt < 2; ++rt) {
    const int rl0 = rbase + rt * 16 + ((lane >> 4) << 2);
#pragma unroll
    for (int ct = 0; ct < 4; ++ct) {
      const int col = ct * 16 + (lane & 15);
      const float bgc = bg[col];
#pragma unroll
      for (int j = 0; j < 4; ++j) {
        const int rl = rl0 + j;
        const int li = (int)((R0 + rl) & (LL - 1));
        const float o = ob[(size_t)li * DD + col];
        const float pre = acc[rt][ct][j] + bgc;
        const float tv = o / (1.f + __expf(-pre));
        const float hf = bf16_hi_f(tv);
        XH[rl * 72 + col] = (unsigned short)bf16_rne(tv);
        XL[rl * 72 + col] = (unsigned short)bf16_rne(tv - hf);
      }
    }
  }
  __syncthreads();

  // restage Wout pack
#pragma unroll
  for (int i = 0; i < 16; ++i) Bl[i * 256 + t] = Bpk[4096 + i * 256 + t];
  __syncthreads();

  // mv2: out = t @ Wout + bout
#pragma unroll
  for (int rt = 0; rt < 2; ++rt)
#pragma unroll
    for (int ct = 0; ct < 4; ++ct) {
      const float bo = bout[ct * 16 + (lane & 15)];
      acc[rt][ct] = f32x4{bo, bo, bo, bo};
    }
  run_mv(acc);

#pragma unroll
  for (int rt = 0; rt < 2; ++rt) {
#pragma unroll
    for (int j = 0; j < 4; ++j) {
      const size_t rg = R0 + rbase + rt * 16 + ((lane >> 4) << 2) + j;
#pragma unroll
      for (int ct = 0; ct < 4; ++ct)
        out[rg * DD + ct * 16 + (lane & 15)] = acc[rt][ct][j];
    }
  }
}

// ---------------------------------------------------------------------------
extern "C" void kernel_launch(void* const* d_in, const int* in_sizes, int n_in,
                              void* d_out, int out_size, void* d_ws, size_t ws_size,
                              hipStream_t stream)
{
  const float* msa  = (const float*)d_in[0];
  const float* lnw  = (const float*)d_in[1];
  const float* lnb  = (const float*)d_in[2];
  const float* Wq   = (const float*)d_in[3];
  const float* Wk   = (const float*)d_in[4];
  const float* Wv   = (const float*)d_in[5];
  const float* Wg   = (const float*)d_in[6];
  const float* bg   = (const float*)d_in[7];
  const float* Wout = (const float*)d_in[8];
  const float* bout = (const float*)d_in[9];
  float* out = (float*)d_out;

  float* kb   = (float*)d_ws;                       // (L, N, 8) 16 MB
  float* vb   = kb + (size_t)LL * NN * 8;           // (L, N, 8) 16 MB
  float* xbar = vb + (size_t)LL * NN * 8;           // (L, 64)  256 KB
  float* ob   = xbar + (size_t)LL * DD;             // (L, 64)  256 KB
  unsigned* Bpk = (unsigned*)(ob + (size_t)LL * DD);// 32 KB packed weights

  kW<<<32, 256, 0, stream>>>(Wg, Wout, Bpk);
  kA<<<LL, 256, 0, stream>>>(msa, lnw, lnb, Wk, Wv, kb, vb, xbar);
  kB<<<LL, 512, 0, stream>>>(kb, vb, xbar, Wq, ob);
  kC<<<(NN * LL) / 128, 256, 0, stream>>>(msa, lnw, lnb, Bpk, bg, ob, bout, out);
}

// Round 5
// 141.649 us; speedup vs baseline: 5.7397x; 1.7204x over previous
//
#include <hip/hip_runtime.h>
#include <math.h>

#define DD 64
#define NN 512
#define LL 1024
#define EPSF 1e-5f
#define NCH 32   // n-chunks (xbar partials per l)

typedef short short8 __attribute__((ext_vector_type(8)));
typedef float f32x4 __attribute__((ext_vector_type(4)));

static __device__ __forceinline__ unsigned bf16_rne(float f) {
  unsigned u = __float_as_uint(f);
  return (u + 0x7FFFu + ((u >> 16) & 1u)) >> 16;
}
static __device__ __forceinline__ float bf16_hi_f(float f) {
  unsigned u = __float_as_uint(f);
  return __uint_as_float((u + 0x7FFFu + ((u >> 16) & 1u)) & 0xFFFF0000u);
}

// ---------------------------------------------------------------------------
// Kernel W: pack Wg/Wout into MFMA B-fragment order, split bf16 hi/lo.
// ---------------------------------------------------------------------------
__global__ __launch_bounds__(256) void kW(const float* __restrict__ Wg,
                                          const float* __restrict__ Wout,
                                          unsigned* __restrict__ Bpk)
{
  const int idx = blockIdx.x * 256 + threadIdx.x;   // 0..8191
  const int e2   = idx & 3;
  const int lane = (idx >> 2) & 63;
  const int ctkt = (idx >> 8) & 7;
  const int h    = (idx >> 11) & 1;
  const int mv   = (idx >> 12) & 1;
  const int col  = ((ctkt >> 1) << 4) | (lane & 15);
  const int k0   = ((ctkt & 1) << 5) + ((lane >> 4) << 3) + (e2 << 1);
  const float* W = mv ? Wout : Wg;
  const float w0 = W[k0 * DD + col];
  const float w1 = W[(k0 + 1) * DD + col];
  unsigned b0, b1;
  if (h == 0) { b0 = bf16_rne(w0); b1 = bf16_rne(w1); }
  else        { b0 = bf16_rne(w0 - bf16_hi_f(w0)); b1 = bf16_rne(w1 - bf16_hi_f(w1)); }
  Bpk[idx] = b0 | (b1 << 16);
}

// ---------------------------------------------------------------------------
// Kernel A v3: block = 16 l x 16 n rows (grid = 32 n-chunks x 64 l-tiles).
// Thread = one row in regs (X[64], compile-time indices only; NO accumulator
// array -> no spill). LN + k/v proj; xbar via 2-step butterfly across the 4
// same-l lanes of each wave + LDS combine across waves -> xbarP partial.
// Loads arrive as 4KB-contiguous granules (16 consecutive l per lane group).
// ---------------------------------------------------------------------------
__global__ __launch_bounds__(256, 4) void kA(
    const float* __restrict__ msa, const float* __restrict__ lnw, const float* __restrict__ lnb,
    const float* __restrict__ Wk, const float* __restrict__ Wv,
    float* __restrict__ kb, float* __restrict__ vb, float* __restrict__ xbarP)
{
  __shared__ float xc[4][16][68];   // 17408 B: per-wave xn-sum quarters
  const int t = threadIdx.x;
  const int lane = t & 63;
  const int w = t >> 6;
  const int l_loc = t & 15;
  const int n_loc = t >> 4;            // 0..15
  const int lt = blockIdx.x & 63;      // l-tile
  const int nc = blockIdx.x >> 6;      // n-chunk 0..31
  const int l0 = lt * 16;
  const int n = nc * 16 + n_loc;
  const int l = l0 + l_loc;

  // load row (n, l): per instr a wave covers 4 x 4KB contiguous segments
  float X[DD];
  {
    const float4* rp = (const float4*)(msa + ((size_t)n * LL + l) * DD);
#pragma unroll
    for (int i = 0; i < 16; ++i) {
      const float4 f = rp[i];
      X[4*i+0] = f.x; X[4*i+1] = f.y; X[4*i+2] = f.z; X[4*i+3] = f.w;
    }
  }

  // LN stats
  float s = 0.f, s2 = 0.f;
#pragma unroll
  for (int d = 0; d < DD; ++d) { s += X[d]; s2 = fmaf(X[d], X[d], s2); }
  const float mu = s * (1.f / DD);
  const float rs = rsqrtf(fmaf(-mu, mu, s2 * (1.f / DD)) + EPSF);

  // xn (overwrite X) + k/v projections (Wk/Wv 4KB -> scalar-cache s_loads)
  float ka[8], va[8];
#pragma unroll
  for (int j = 0; j < 8; ++j) { ka[j] = 0.f; va[j] = 0.f; }
#pragma unroll
  for (int d = 0; d < DD; ++d) {
    const float xn = fmaf((X[d] - mu) * rs, lnw[d], lnb[d]);
    X[d] = xn;
#pragma unroll
    for (int j = 0; j < 8; ++j) {
      ka[j] = fmaf(xn, Wk[d * 8 + j], ka[j]);
      va[j] = fmaf(xn, Wv[d * 8 + j], va[j]);
    }
  }

  // k/v store: per instr 16 x 128B aligned contiguous chunks
  {
    float4* kp = (float4*)(kb + ((size_t)l * NN + n) * 8);
    float4* vp = (float4*)(vb + ((size_t)l * NN + n) * 8);
    kp[0] = make_float4(ka[0], ka[1], ka[2], ka[3]);
    kp[1] = make_float4(ka[4], ka[5], ka[6], ka[7]);
    vp[0] = make_float4(va[0], va[1], va[2], va[3]);
    vp[1] = make_float4(va[4], va[5], va[6], va[7]);
  }

  // butterfly over the 4 same-l lanes (lane ^ 16, lane ^ 32): vector halving
  // 64 -> 32 -> 16. After: lane holds elements [d0, d0+16) summed over its
  // wave's 4 n's, d0 = 32*bit4(lane) + 16*bit5(lane).
  {
    const bool hi1 = (lane & 16) != 0;
#pragma unroll
    for (int k = 0; k < 32; ++k) {
      const float keep = hi1 ? X[k + 32] : X[k];
      const float send = hi1 ? X[k] : X[k + 32];
      X[k] = keep + __shfl_xor(send, 16);
    }
    const bool hi2 = (lane & 32) != 0;
#pragma unroll
    for (int k = 0; k < 16; ++k) {
      const float keep = hi2 ? X[k + 16] : X[k];
      const float send = hi2 ? X[k] : X[k + 16];
      X[k] = keep + __shfl_xor(send, 32);
    }
  }
  const int d0 = ((lane >> 4) & 1) * 32 + (lane >> 5) * 16;
#pragma unroll
  for (int k = 0; k < 16; ++k) xc[w][l_loc][d0 + k] = X[k];
  __syncthreads();

  // combine 4 waves -> xbarP[l][nc][d]
#pragma unroll
  for (int j = 0; j < 4; ++j) {
    const int c = t * 4 + j;            // 0..1023
    const int ll = c >> 6, d = c & 63;
    const float sv = xc[0][ll][d] + xc[1][ll][d] + xc[2][ll][d] + xc[3][ll][d];
    xbarP[((size_t)(l0 + ll) * NCH + nc) * DD + d] = sv;
  }
}

// ---------------------------------------------------------------------------
// Kernel B: per l: xbar = (1/N) sum of partials; q = xbar@Wq (scaled);
// scores over n, softmax, o = attn@v. 512 thr = 8 waves; wave h = head h.
// ---------------------------------------------------------------------------
__global__ __launch_bounds__(512) void kB(
    const float* __restrict__ kb, const float* __restrict__ vb,
    const float* __restrict__ xbarP, const float* __restrict__ Wq,
    float* __restrict__ ob)
{
  __shared__ float xbL[DD];
  __shared__ float qs[DD];
  __shared__ float ks[NN * 9];
  __shared__ float vs[NN * 9];
  const int l = blockIdx.x;
  const int t = threadIdx.x;
  const int h = t >> 6;
  const int lane = t & 63;

  const float* kl = kb + (size_t)l * NN * 8;
  const float* vl = vb + (size_t)l * NN * 8;
#pragma unroll
  for (int i = 0; i < 8; ++i) {
    const int idx = i * 512 + t;
    const int n = idx >> 3, j = idx & 7;
    ks[n*9 + j] = kl[idx];
    vs[n*9 + j] = vl[idx];
  }
  if (t < DD) {
    float s = 0.f;
    for (int p = 0; p < NCH; ++p) s += xbarP[((size_t)l * NCH + p) * DD + t];
    xbL[t] = s * (1.f / NN);
  }
  __syncthreads();
  if (t < DD) {
    float acc = 0.f;
    for (int d = 0; d < DD; ++d) acc = fmaf(xbL[d], Wq[d*DD + t], acc);
    qs[t] = acc * 0.35355339059327373f;
  }
  __syncthreads();

  float sc[8];
  float m = -1e30f;
#pragma unroll
  for (int i = 0; i < 8; ++i) {
    const int n = i * 64 + lane;
    float s = 0.f;
#pragma unroll
    for (int d = 0; d < 8; ++d) s = fmaf(qs[h*8 + d], ks[n*9 + d], s);
    sc[i] = s;
    m = fmaxf(m, s);
  }
#pragma unroll
  for (int off = 32; off; off >>= 1) m = fmaxf(m, __shfl_xor(m, off));
  float ssum = 0.f;
#pragma unroll
  for (int i = 0; i < 8; ++i) { sc[i] = __expf(sc[i] - m); ssum += sc[i]; }
#pragma unroll
  for (int off = 32; off; off >>= 1) ssum += __shfl_xor(ssum, off);
  const float inv = 1.f / ssum;

  float oacc[8];
#pragma unroll
  for (int d = 0; d < 8; ++d) oacc[d] = 0.f;
#pragma unroll
  for (int i = 0; i < 8; ++i) {
    const int n = i * 64 + lane;
#pragma unroll
    for (int d = 0; d < 8; ++d) oacc[d] = fmaf(sc[i], vs[n*9 + d], oacc[d]);
  }
#pragma unroll
  for (int d = 0; d < 8; ++d) {
#pragma unroll
    for (int off = 32; off; off >>= 1) oacc[d] += __shfl_xor(oacc[d], off);
  }
  if (lane == 0) {
    float4* op = (float4*)(ob + (size_t)l * DD + h * 8);
    op[0] = make_float4(oacc[0]*inv, oacc[1]*inv, oacc[2]*inv, oacc[3]*inv);
    op[1] = make_float4(oacc[4]*inv, oacc[5]*inv, oacc[6]*inv, oacc[7]*inv);
  }
}

// ---------------------------------------------------------------------------
// Kernel C (MFMA, split-bf16 3-term): unchanged from R4.
// ---------------------------------------------------------------------------
__global__ __launch_bounds__(256, 4) void kC(
    const float* __restrict__ msa, const float* __restrict__ lnw, const float* __restrict__ lnb,
    const unsigned* __restrict__ Bpk, const float* __restrict__ bg,
    const float* __restrict__ ob, const float* __restrict__ bout,
    float* __restrict__ out)
{
  __shared__ unsigned Bl[4096];            // 16 KB
  __shared__ unsigned short XH[128 * 72];  // 18 KB
  __shared__ unsigned short XL[128 * 72];  // 18 KB
  const int t = threadIdx.x;
  const int lane = t & 63;
  const int w = t >> 6;
  const int rbase = 32 * w;
  const size_t R0 = (size_t)blockIdx.x * 128;

#pragma unroll
  for (int i = 0; i < 16; ++i) Bl[i * 256 + t] = Bpk[i * 256 + t];

  if (t < 128) {
    const float4* rp = (const float4*)(msa + (R0 + t) * DD);
    float4 r4[16];
#pragma unroll
    for (int i = 0; i < 16; ++i) r4[i] = rp[i];
    float s = 0.f, s2 = 0.f;
#pragma unroll
    for (int i = 0; i < 16; ++i) {
      const float4 f = r4[i];
      s += (f.x + f.y) + (f.z + f.w);
      s2 = fmaf(f.x, f.x, s2); s2 = fmaf(f.y, f.y, s2);
      s2 = fmaf(f.z, f.z, s2); s2 = fmaf(f.w, f.w, s2);
    }
    const float mu = s * (1.f / DD);
    const float rs = rsqrtf(fmaf(-mu, mu, s2 * (1.f / DD)) + EPSF);
    const float aa = rs, bb = -mu * rs;
#pragma unroll
    for (int i = 0; i < 16; ++i) {
      const float xs0 = r4[i].x, xs1 = r4[i].y, xs2 = r4[i].z, xs3 = r4[i].w;
      unsigned hh[4], ll[4];
#define XN_SPLIT(c, xv)                                               \
      {                                                               \
        const int d = 4 * i + (c);                                    \
        const float xn = fmaf(fmaf((xv), aa, bb), lnw[d], lnb[d]);    \
        const float hf = bf16_hi_f(xn);                               \
        hh[c] = bf16_rne(xn);                                         \
        ll[c] = bf16_rne(xn - hf);                                    \
      }
      XN_SPLIT(0, xs0) XN_SPLIT(1, xs1) XN_SPLIT(2, xs2) XN_SPLIT(3, xs3)
#undef XN_SPLIT
      *(uint2*)&XH[t * 72 + 4 * i] = make_uint2(hh[0] | (hh[1] << 16), hh[2] | (hh[3] << 16));
      *(uint2*)&XL[t * 72 + 4 * i] = make_uint2(ll[0] | (ll[1] << 16), ll[2] | (ll[3] << 16));
    }
  }
  __syncthreads();

  auto run_mv = [&](f32x4 acc[2][4]) {
#pragma unroll
    for (int rt = 0; rt < 2; ++rt) {
      const int row = rbase + rt * 16 + (lane & 15);
      const int kg = (lane >> 4) * 8;
      const short8 ah0 = *(const short8*)&XH[row * 72 + kg];
      const short8 ah1 = *(const short8*)&XH[row * 72 + 32 + kg];
      const short8 al0 = *(const short8*)&XL[row * 72 + kg];
      const short8 al1 = *(const short8*)&XL[row * 72 + 32 + kg];
#pragma unroll
      for (int ct = 0; ct < 4; ++ct) {
        const short8 bh0 = *(const short8*)&Bl[((0 * 8 + ct * 2 + 0) * 64 + lane) * 4];
        const short8 bh1 = *(const short8*)&Bl[((0 * 8 + ct * 2 + 1) * 64 + lane) * 4];
        const short8 bl0 = *(const short8*)&Bl[((1 * 8 + ct * 2 + 0) * 64 + lane) * 4];
        const short8 bl1 = *(const short8*)&Bl[((1 * 8 + ct * 2 + 1) * 64 + lane) * 4];
        f32x4 c = acc[rt][ct];
        c = __builtin_amdgcn_mfma_f32_16x16x32_bf16(ah0, bh0, c, 0, 0, 0);
        c = __builtin_amdgcn_mfma_f32_16x16x32_bf16(ah1, bh1, c, 0, 0, 0);
        c = __builtin_amdgcn_mfma_f32_16x16x32_bf16(ah0, bl0, c, 0, 0, 0);
        c = __builtin_amdgcn_mfma_f32_16x16x32_bf16(ah1, bl1, c, 0, 0, 0);
        c = __builtin_amdgcn_mfma_f32_16x16x32_bf16(al0, bh0, c, 0, 0, 0);
        c = __builtin_amdgcn_mfma_f32_16x16x32_bf16(al1, bh1, c, 0, 0, 0);
        acc[rt][ct] = c;
      }
    }
  };

  f32x4 acc[2][4];
#pragma unroll
  for (int rt = 0; rt < 2; ++rt)
#pragma unroll
    for (int ct = 0; ct < 4; ++ct) acc[rt][ct] = f32x4{0.f, 0.f, 0.f, 0.f};
  run_mv(acc);   // mv1

#pragma unroll
  for (int rt = 0; rt < 2; ++rt) {
    const int rl0 = rbase + rt * 16 + ((lane >> 4) << 2);
#pragma unroll
    for (int ct = 0; ct < 4; ++ct) {
      const int col = ct * 16 + (lane & 15);
      const float bgc = bg[col];
#pragma unroll
      for (int j = 0; j < 4; ++j) {
        const int rl = rl0 + j;
        const int li = (int)((R0 + rl) & (LL - 1));
        const float o = ob[(size_t)li * DD + col];
        const float pre = acc[rt][ct][j] + bgc;
        const float tv = o / (1.f + __expf(-pre));
        const float hf = bf16_hi_f(tv);
        XH[rl * 72 + col] = (unsigned short)bf16_rne(tv);
        XL[rl * 72 + col] = (unsigned short)bf16_rne(tv - hf);
      }
    }
  }
  __syncthreads();

#pragma unroll
  for (int i = 0; i < 16; ++i) Bl[i * 256 + t] = Bpk[4096 + i * 256 + t];
  __syncthreads();

#pragma unroll
  for (int rt = 0; rt < 2; ++rt)
#pragma unroll
    for (int ct = 0; ct < 4; ++ct) {
      const float bo = bout[ct * 16 + (lane & 15)];
      acc[rt][ct] = f32x4{bo, bo, bo, bo};
    }
  run_mv(acc);

#pragma unroll
  for (int rt = 0; rt < 2; ++rt) {
#pragma unroll
    for (int j = 0; j < 4; ++j) {
      const size_t rg = R0 + rbase + rt * 16 + ((lane >> 4) << 2) + j;
#pragma unroll
      for (int ct = 0; ct < 4; ++ct)
        out[rg * DD + ct * 16 + (lane & 15)] = acc[rt][ct][j];
    }
  }
}

// ---------------------------------------------------------------------------
extern "C" void kernel_launch(void* const* d_in, const int* in_sizes, int n_in,
                              void* d_out, int out_size, void* d_ws, size_t ws_size,
                              hipStream_t stream)
{
  const float* msa  = (const float*)d_in[0];
  const float* lnw  = (const float*)d_in[1];
  const float* lnb  = (const float*)d_in[2];
  const float* Wq   = (const float*)d_in[3];
  const float* Wk   = (const float*)d_in[4];
  const float* Wv   = (const float*)d_in[5];
  const float* Wg   = (const float*)d_in[6];
  const float* bg   = (const float*)d_in[7];
  const float* Wout = (const float*)d_in[8];
  const float* bout = (const float*)d_in[9];
  float* out = (float*)d_out;

  float* kb    = (float*)d_ws;                        // (L, N, 8) 16 MB
  float* vb    = kb + (size_t)LL * NN * 8;            // (L, N, 8) 16 MB
  float* xbarP = vb + (size_t)LL * NN * 8;            // (L, 32, 64) 8 MB
  float* ob    = xbarP + (size_t)LL * NCH * DD;       // (L, 64) 256 KB
  unsigned* Bpk = (unsigned*)(ob + (size_t)LL * DD);  // 32 KB packed weights

  kW<<<32, 256, 0, stream>>>(Wg, Wout, Bpk);
  kA<<<64 * NCH, 256, 0, stream>>>(msa, lnw, lnb, Wk, Wv, kb, vb, xbarP);
  kB<<<LL, 512, 0, stream>>>(kb, vb, xbarP, Wq, ob);
  kC<<<(NN * LL) / 128, 256, 0, stream>>>(msa, lnw, lnb, Bpk, bg, ob, bout, out);
}

// Round 6
// 134.126 us; speedup vs baseline: 6.0617x; 1.0561x over previous
//
#include <hip/hip_runtime.h>
#include <math.h>

#define DD 64
#define NN 512
#define LL 1024
#define EPSF 1e-5f
#define NCH 32   // n-chunks (xbar partials per l)

typedef short short8 __attribute__((ext_vector_type(8)));
typedef float f32x4 __attribute__((ext_vector_type(4)));

static __device__ __forceinline__ unsigned bf16_rne(float f) {
  unsigned u = __float_as_uint(f);
  return (u + 0x7FFFu + ((u >> 16) & 1u)) >> 16;
}
static __device__ __forceinline__ float bf16_hi_f(float f) {
  unsigned u = __float_as_uint(f);
  return __uint_as_float((u + 0x7FFFu + ((u >> 16) & 1u)) & 0xFFFF0000u);
}

// ---------------------------------------------------------------------------
// Kernel W: pack Wg/Wout into MFMA B-fragment order, split bf16 hi/lo.
// Bpk short8-frag index: ((mv*2 + h)*8 + ct*2 + kt)*64 + lane
// element: col = ct*16 + (lane&15); k = kt*32 + (lane>>4)*8 + e
// ---------------------------------------------------------------------------
__global__ __launch_bounds__(256) void kW(const float* __restrict__ Wg,
                                          const float* __restrict__ Wout,
                                          unsigned* __restrict__ Bpk)
{
  const int idx = blockIdx.x * 256 + threadIdx.x;   // 0..8191
  const int e2   = idx & 3;
  const int lane = (idx >> 2) & 63;
  const int ctkt = (idx >> 8) & 7;
  const int h    = (idx >> 11) & 1;
  const int mv   = (idx >> 12) & 1;
  const int col  = ((ctkt >> 1) << 4) | (lane & 15);
  const int k0   = ((ctkt & 1) << 5) + ((lane >> 4) << 3) + (e2 << 1);
  const float* W = mv ? Wout : Wg;
  const float w0 = W[k0 * DD + col];
  const float w1 = W[(k0 + 1) * DD + col];
  unsigned b0, b1;
  if (h == 0) { b0 = bf16_rne(w0); b1 = bf16_rne(w1); }
  else        { b0 = bf16_rne(w0 - bf16_hi_f(w0)); b1 = bf16_rne(w1 - bf16_hi_f(w1)); }
  Bpk[idx] = b0 | (b1 << 16);
}

// ---------------------------------------------------------------------------
// Kernel A: unchanged from R5 (proven). block = 16 l x 16 n rows; thread =
// one row in regs; LN + k/v proj; xbar partial via butterfly + LDS combine.
// ---------------------------------------------------------------------------
__global__ __launch_bounds__(256, 4) void kA(
    const float* __restrict__ msa, const float* __restrict__ lnw, const float* __restrict__ lnb,
    const float* __restrict__ Wk, const float* __restrict__ Wv,
    float* __restrict__ kb, float* __restrict__ vb, float* __restrict__ xbarP)
{
  __shared__ float xc[4][16][68];
  const int t = threadIdx.x;
  const int lane = t & 63;
  const int w = t >> 6;
  const int l_loc = t & 15;
  const int n_loc = t >> 4;
  const int lt = blockIdx.x & 63;
  const int nc = blockIdx.x >> 6;
  const int l0 = lt * 16;
  const int n = nc * 16 + n_loc;
  const int l = l0 + l_loc;

  float X[DD];
  {
    const float4* rp = (const float4*)(msa + ((size_t)n * LL + l) * DD);
#pragma unroll
    for (int i = 0; i < 16; ++i) {
      const float4 f = rp[i];
      X[4*i+0] = f.x; X[4*i+1] = f.y; X[4*i+2] = f.z; X[4*i+3] = f.w;
    }
  }

  float s = 0.f, s2 = 0.f;
#pragma unroll
  for (int d = 0; d < DD; ++d) { s += X[d]; s2 = fmaf(X[d], X[d], s2); }
  const float mu = s * (1.f / DD);
  const float rs = rsqrtf(fmaf(-mu, mu, s2 * (1.f / DD)) + EPSF);

  float ka[8], va[8];
#pragma unroll
  for (int j = 0; j < 8; ++j) { ka[j] = 0.f; va[j] = 0.f; }
#pragma unroll
  for (int d = 0; d < DD; ++d) {
    const float xn = fmaf((X[d] - mu) * rs, lnw[d], lnb[d]);
    X[d] = xn;
#pragma unroll
    for (int j = 0; j < 8; ++j) {
      ka[j] = fmaf(xn, Wk[d * 8 + j], ka[j]);
      va[j] = fmaf(xn, Wv[d * 8 + j], va[j]);
    }
  }

  {
    float4* kp = (float4*)(kb + ((size_t)l * NN + n) * 8);
    float4* vp = (float4*)(vb + ((size_t)l * NN + n) * 8);
    kp[0] = make_float4(ka[0], ka[1], ka[2], ka[3]);
    kp[1] = make_float4(ka[4], ka[5], ka[6], ka[7]);
    vp[0] = make_float4(va[0], va[1], va[2], va[3]);
    vp[1] = make_float4(va[4], va[5], va[6], va[7]);
  }

  {
    const bool hi1 = (lane & 16) != 0;
#pragma unroll
    for (int k = 0; k < 32; ++k) {
      const float keep = hi1 ? X[k + 32] : X[k];
      const float send = hi1 ? X[k] : X[k + 32];
      X[k] = keep + __shfl_xor(send, 16);
    }
    const bool hi2 = (lane & 32) != 0;
#pragma unroll
    for (int k = 0; k < 16; ++k) {
      const float keep = hi2 ? X[k + 16] : X[k];
      const float send = hi2 ? X[k] : X[k + 16];
      X[k] = keep + __shfl_xor(send, 32);
    }
  }
  const int d0 = ((lane >> 4) & 1) * 32 + (lane >> 5) * 16;
#pragma unroll
  for (int k = 0; k < 16; ++k) xc[w][l_loc][d0 + k] = X[k];
  __syncthreads();

#pragma unroll
  for (int j = 0; j < 4; ++j) {
    const int c = t * 4 + j;
    const int ll = c >> 6, d = c & 63;
    const float sv = xc[0][ll][d] + xc[1][ll][d] + xc[2][ll][d] + xc[3][ll][d];
    xbarP[((size_t)(l0 + ll) * NCH + nc) * DD + d] = sv;
  }
}

// ---------------------------------------------------------------------------
// Kernel B: as R5 but writes obT[d][l] (transposed) so kC gate loads are
// float4 over l.
// ---------------------------------------------------------------------------
__global__ __launch_bounds__(512) void kB(
    const float* __restrict__ kb, const float* __restrict__ vb,
    const float* __restrict__ xbarP, const float* __restrict__ Wq,
    float* __restrict__ obT)
{
  __shared__ float xbL[DD];
  __shared__ float qs[DD];
  __shared__ float ks[NN * 9];
  __shared__ float vs[NN * 9];
  const int l = blockIdx.x;
  const int t = threadIdx.x;
  const int h = t >> 6;
  const int lane = t & 63;

  const float* kl = kb + (size_t)l * NN * 8;
  const float* vl = vb + (size_t)l * NN * 8;
#pragma unroll
  for (int i = 0; i < 8; ++i) {
    const int idx = i * 512 + t;
    const int n = idx >> 3, j = idx & 7;
    ks[n*9 + j] = kl[idx];
    vs[n*9 + j] = vl[idx];
  }
  if (t < DD) {
    float s = 0.f;
    for (int p = 0; p < NCH; ++p) s += xbarP[((size_t)l * NCH + p) * DD + t];
    xbL[t] = s * (1.f / NN);
  }
  __syncthreads();
  if (t < DD) {
    float acc = 0.f;
    for (int d = 0; d < DD; ++d) acc = fmaf(xbL[d], Wq[d*DD + t], acc);
    qs[t] = acc * 0.35355339059327373f;
  }
  __syncthreads();

  float sc[8];
  float m = -1e30f;
#pragma unroll
  for (int i = 0; i < 8; ++i) {
    const int n = i * 64 + lane;
    float s = 0.f;
#pragma unroll
    for (int d = 0; d < 8; ++d) s = fmaf(qs[h*8 + d], ks[n*9 + d], s);
    sc[i] = s;
    m = fmaxf(m, s);
  }
#pragma unroll
  for (int off = 32; off; off >>= 1) m = fmaxf(m, __shfl_xor(m, off));
  float ssum = 0.f;
#pragma unroll
  for (int i = 0; i < 8; ++i) { sc[i] = __expf(sc[i] - m); ssum += sc[i]; }
#pragma unroll
  for (int off = 32; off; off >>= 1) ssum += __shfl_xor(ssum, off);
  const float inv = 1.f / ssum;

  float oacc[8];
#pragma unroll
  for (int d = 0; d < 8; ++d) oacc[d] = 0.f;
#pragma unroll
  for (int i = 0; i < 8; ++i) {
    const int n = i * 64 + lane;
#pragma unroll
    for (int d = 0; d < 8; ++d) oacc[d] = fmaf(sc[i], vs[n*9 + d], oacc[d]);
  }
#pragma unroll
  for (int d = 0; d < 8; ++d) {
#pragma unroll
    for (int off = 32; off; off >>= 1) oacc[d] += __shfl_xor(oacc[d], off);
  }
  if (lane == 0) {
#pragma unroll
    for (int d = 0; d < 8; ++d)
      obT[(size_t)(h * 8 + d) * LL + l] = oacc[d] * inv;
  }
}

// ---------------------------------------------------------------------------
// Kernel C v3 (zero-barrier): 128 rows/block, 256 thr = 4 waves.
// Thread t owns half-row (row=t>>1, half=t&1): all threads load msa; LN via
// shfl_xor(1). Wave w's threads write exactly LDS rows 32w..32w+31 = the rows
// its MFMA A-frags + sigmoid phase touch -> everything wave-private, NO
// __syncthreads anywhere. B-frags read per-ct from global Bpk (L2-resident,
// coalesced 1KB/instr). LDS 36 KB -> 4 blocks/CU.
// A-frag: lane holds row=(lane&15), k=8*(lane>>4)+e.
// C/D: reg j -> row=(lane>>4)*4+j, col=lane&15.
// ---------------------------------------------------------------------------
__global__ __launch_bounds__(256, 4) void kC(
    const float* __restrict__ msa, const float* __restrict__ lnw, const float* __restrict__ lnb,
    const unsigned* __restrict__ Bpk, const float* __restrict__ bg,
    const float* __restrict__ obT, const float* __restrict__ bout,
    float* __restrict__ out)
{
  __shared__ unsigned short XH[128 * 72];  // 18 KB
  __shared__ unsigned short XL[128 * 72];  // 18 KB
  const int t = threadIdx.x;
  const int lane = t & 63;
  const int w = t >> 6;
  const int rbase = 32 * w;
  const size_t R0 = (size_t)blockIdx.x * 128;
  const int row = t >> 1;     // local row 0..127
  const int half = t & 1;     // 32-elem half

  // ---- all-thread load + paired LN + split-bf16 -> LDS ----
  {
    const float4* rp = (const float4*)(msa + (R0 + row) * DD + half * 32);
    float4 r4[8];
#pragma unroll
    for (int i = 0; i < 8; ++i) r4[i] = rp[i];
    float s = 0.f, s2 = 0.f;
#pragma unroll
    for (int i = 0; i < 8; ++i) {
      const float4 f = r4[i];
      s += (f.x + f.y) + (f.z + f.w);
      s2 = fmaf(f.x, f.x, s2); s2 = fmaf(f.y, f.y, s2);
      s2 = fmaf(f.z, f.z, s2); s2 = fmaf(f.w, f.w, s2);
    }
    s += __shfl_xor(s, 1);
    s2 += __shfl_xor(s2, 1);
    const float mu = s * (1.f / DD);
    const float rs = rsqrtf(fmaf(-mu, mu, s2 * (1.f / DD)) + EPSF);
    const float aa = rs, bb = -mu * rs;
#pragma unroll
    for (int i = 0; i < 8; ++i) {
      const float xs0 = r4[i].x, xs1 = r4[i].y, xs2 = r4[i].z, xs3 = r4[i].w;
      unsigned hh[4], ll[4];
#define XN_SPLIT(c, xv)                                               \
      {                                                               \
        const int d = half * 32 + 4 * i + (c);                        \
        const float xn = fmaf(fmaf((xv), aa, bb), lnw[d], lnb[d]);    \
        const float hf = bf16_hi_f(xn);                               \
        hh[c] = bf16_rne(xn);                                         \
        ll[c] = bf16_rne(xn - hf);                                    \
      }
      XN_SPLIT(0, xs0) XN_SPLIT(1, xs1) XN_SPLIT(2, xs2) XN_SPLIT(3, xs3)
#undef XN_SPLIT
      *(uint2*)&XH[row * 72 + half * 32 + 4 * i] =
          make_uint2(hh[0] | (hh[1] << 16), hh[2] | (hh[3] << 16));
      *(uint2*)&XL[row * 72 + half * 32 + 4 * i] =
          make_uint2(ll[0] | (ll[1] << 16), ll[2] | (ll[3] << 16));
    }
  }
  // no barrier: rows 32w..32w+31 written & read only by wave w

  const short8* Bp = (const short8*)Bpk;   // frag*64 + lane

  auto run_mv = [&](int mvsel, f32x4 acc[2][4]) {
    short8 ah[2][2], al[2][2];
#pragma unroll
    for (int rt = 0; rt < 2; ++rt) {
      const int ar = rbase + rt * 16 + (lane & 15);
      const int kg = (lane >> 4) * 8;
      ah[rt][0] = *(const short8*)&XH[ar * 72 + kg];
      ah[rt][1] = *(const short8*)&XH[ar * 72 + 32 + kg];
      al[rt][0] = *(const short8*)&XL[ar * 72 + kg];
      al[rt][1] = *(const short8*)&XL[ar * 72 + 32 + kg];
    }
#pragma unroll
    for (int ct = 0; ct < 4; ++ct) {
      const short8 bh0 = Bp[((mvsel * 2 + 0) * 8 + ct * 2 + 0) * 64 + lane];
      const short8 bh1 = Bp[((mvsel * 2 + 0) * 8 + ct * 2 + 1) * 64 + lane];
      const short8 bl0 = Bp[((mvsel * 2 + 1) * 8 + ct * 2 + 0) * 64 + lane];
      const short8 bl1 = Bp[((mvsel * 2 + 1) * 8 + ct * 2 + 1) * 64 + lane];
#pragma unroll
      for (int rt = 0; rt < 2; ++rt) {
        f32x4 c = acc[rt][ct];
        c = __builtin_amdgcn_mfma_f32_16x16x32_bf16(ah[rt][0], bh0, c, 0, 0, 0);
        c = __builtin_amdgcn_mfma_f32_16x16x32_bf16(ah[rt][1], bh1, c, 0, 0, 0);
        c = __builtin_amdgcn_mfma_f32_16x16x32_bf16(ah[rt][0], bl0, c, 0, 0, 0);
        c = __builtin_amdgcn_mfma_f32_16x16x32_bf16(ah[rt][1], bl1, c, 0, 0, 0);
        c = __builtin_amdgcn_mfma_f32_16x16x32_bf16(al[rt][0], bh0, c, 0, 0, 0);
        c = __builtin_amdgcn_mfma_f32_16x16x32_bf16(al[rt][1], bh1, c, 0, 0, 0);
        acc[rt][ct] = c;
      }
    }
  };

  f32x4 acc[2][4];
#pragma unroll
  for (int rt = 0; rt < 2; ++rt)
#pragma unroll
    for (int ct = 0; ct < 4; ++ct) acc[rt][ct] = f32x4{0.f, 0.f, 0.f, 0.f};
  run_mv(0, acc);   // mv1: gate pre-activation

  // sigmoid * o -> t, split-bf16 back into wave-private rows
#pragma unroll
  for (int rt = 0; rt < 2; ++rt) {
    const int rl0 = rbase + rt * 16 + ((lane >> 4) << 2);
    const int li0 = (int)((R0 + rl0) & (LL - 1));
#pragma unroll
    for (int ct = 0; ct < 4; ++ct) {
      const int col = ct * 16 + (lane & 15);
      const float4 ov = *(const float4*)&obT[(size_t)col * LL + li0];
      const float bgc = bg[col];
      const float o0 = ov.x, o1 = ov.y, o2 = ov.z, o3 = ov.w;
#define SIG_STORE(j, ocomp)                                           \
      {                                                               \
        const float pre = acc[rt][ct][j] + bgc;                       \
        const float tv = (ocomp) / (1.f + __expf(-pre));              \
        const float hf = bf16_hi_f(tv);                               \
        XH[(rl0 + (j)) * 72 + col] = (unsigned short)bf16_rne(tv);    \
        XL[(rl0 + (j)) * 72 + col] = (unsigned short)bf16_rne(tv - hf); \
      }
      SIG_STORE(0, o0) SIG_STORE(1, o1) SIG_STORE(2, o2) SIG_STORE(3, o3)
#undef SIG_STORE
    }
  }
  // no barrier: wave-private rows

  // mv2: out = t @ Wout + bout
#pragma unroll
  for (int rt = 0; rt < 2; ++rt)
#pragma unroll
    for (int ct = 0; ct < 4; ++ct) {
      const float bo = bout[ct * 16 + (lane & 15)];
      acc[rt][ct] = f32x4{bo, bo, bo, bo};
    }
  run_mv(1, acc);

#pragma unroll
  for (int rt = 0; rt < 2; ++rt) {
#pragma unroll
    for (int j = 0; j < 4; ++j) {
      const size_t rg = R0 + rbase + rt * 16 + ((lane >> 4) << 2) + j;
#pragma unroll
      for (int ct = 0; ct < 4; ++ct)
        out[rg * DD + ct * 16 + (lane & 15)] = acc[rt][ct][j];
    }
  }
}

// ---------------------------------------------------------------------------
extern "C" void kernel_launch(void* const* d_in, const int* in_sizes, int n_in,
                              void* d_out, int out_size, void* d_ws, size_t ws_size,
                              hipStream_t stream)
{
  const float* msa  = (const float*)d_in[0];
  const float* lnw  = (const float*)d_in[1];
  const float* lnb  = (const float*)d_in[2];
  const float* Wq   = (const float*)d_in[3];
  const float* Wk   = (const float*)d_in[4];
  const float* Wv   = (const float*)d_in[5];
  const float* Wg   = (const float*)d_in[6];
  const float* bg   = (const float*)d_in[7];
  const float* Wout = (const float*)d_in[8];
  const float* bout = (const float*)d_in[9];
  float* out = (float*)d_out;

  float* kb    = (float*)d_ws;                        // (L, N, 8) 16 MB
  float* vb    = kb + (size_t)LL * NN * 8;            // (L, N, 8) 16 MB
  float* xbarP = vb + (size_t)LL * NN * 8;            // (L, 32, 64) 8 MB
  float* obT   = xbarP + (size_t)LL * NCH * DD;       // (64, L) 256 KB
  unsigned* Bpk = (unsigned*)(obT + (size_t)DD * LL); // 32 KB packed weights

  kW<<<32, 256, 0, stream>>>(Wg, Wout, Bpk);
  kA<<<64 * NCH, 256, 0, stream>>>(msa, lnw, lnb, Wk, Wv, kb, vb, xbarP);
  kB<<<LL, 512, 0, stream>>>(kb, vb, xbarP, Wq, obT);
  kC<<<(NN * LL) / 128, 256, 0, stream>>>(msa, lnw, lnb, Bpk, bg, obT, bout, out);
}

// Round 7
// 132.488 us; speedup vs baseline: 6.1366x; 1.0124x over previous
//
#include <hip/hip_runtime.h>
#include <math.h>

#define DD 64
#define NN 512
#define LL 1024
#define EPSF 1e-5f
#define NCH 32   // n-chunks (xbar partials per l)

typedef short short8 __attribute__((ext_vector_type(8)));
typedef float f32x4 __attribute__((ext_vector_type(4)));

static __device__ __forceinline__ unsigned bf16_rne(float f) {
  unsigned u = __float_as_uint(f);
  return (u + 0x7FFFu + ((u >> 16) & 1u)) >> 16;
}
static __device__ __forceinline__ float bf16_hi_f(float f) {
  unsigned u = __float_as_uint(f);
  return __uint_as_float((u + 0x7FFFu + ((u >> 16) & 1u)) & 0xFFFF0000u);
}
// HW packed convert: [bf16(a) | bf16(b)<<16]
static __device__ __forceinline__ unsigned cvt_pk_bf16(float a, float b) {
  unsigned r;
  asm("v_cvt_pk_bf16_f32 %0, %1, %2" : "=v"(r) : "v"(a), "v"(b));
  return r;
}

// ---------------------------------------------------------------------------
// Kernel W: pack Wg/Wout into MFMA B-fragment order, split bf16 hi/lo.
// Bpk short8-frag index: ((mv*2 + h)*8 + ct*2 + kt)*64 + lane
// element: col = ct*16 + (lane&15); k = kt*32 + (lane>>4)*8 + e
// ---------------------------------------------------------------------------
__global__ __launch_bounds__(256) void kW(const float* __restrict__ Wg,
                                          const float* __restrict__ Wout,
                                          unsigned* __restrict__ Bpk)
{
  const int idx = blockIdx.x * 256 + threadIdx.x;   // 0..8191
  const int e2   = idx & 3;
  const int lane = (idx >> 2) & 63;
  const int ctkt = (idx >> 8) & 7;
  const int h    = (idx >> 11) & 1;
  const int mv   = (idx >> 12) & 1;
  const int col  = ((ctkt >> 1) << 4) | (lane & 15);
  const int k0   = ((ctkt & 1) << 5) + ((lane >> 4) << 3) + (e2 << 1);
  const float* W = mv ? Wout : Wg;
  const float w0 = W[k0 * DD + col];
  const float w1 = W[(k0 + 1) * DD + col];
  unsigned b0, b1;
  if (h == 0) { b0 = bf16_rne(w0); b1 = bf16_rne(w1); }
  else        { b0 = bf16_rne(w0 - bf16_hi_f(w0)); b1 = bf16_rne(w1 - bf16_hi_f(w1)); }
  Bpk[idx] = b0 | (b1 << 16);
}

// ---------------------------------------------------------------------------
// Kernel A: unchanged (proven). block = 16 l x 16 n rows; thread = one row
// in regs; LN + k/v proj; xbar partial via butterfly + LDS combine.
// ---------------------------------------------------------------------------
__global__ __launch_bounds__(256, 4) void kA(
    const float* __restrict__ msa, const float* __restrict__ lnw, const float* __restrict__ lnb,
    const float* __restrict__ Wk, const float* __restrict__ Wv,
    float* __restrict__ kb, float* __restrict__ vb, float* __restrict__ xbarP)
{
  __shared__ float xc[4][16][68];
  const int t = threadIdx.x;
  const int lane = t & 63;
  const int w = t >> 6;
  const int l_loc = t & 15;
  const int n_loc = t >> 4;
  const int lt = blockIdx.x & 63;
  const int nc = blockIdx.x >> 6;
  const int l0 = lt * 16;
  const int n = nc * 16 + n_loc;
  const int l = l0 + l_loc;

  float X[DD];
  {
    const float4* rp = (const float4*)(msa + ((size_t)n * LL + l) * DD);
#pragma unroll
    for (int i = 0; i < 16; ++i) {
      const float4 f = rp[i];
      X[4*i+0] = f.x; X[4*i+1] = f.y; X[4*i+2] = f.z; X[4*i+3] = f.w;
    }
  }

  float s = 0.f, s2 = 0.f;
#pragma unroll
  for (int d = 0; d < DD; ++d) { s += X[d]; s2 = fmaf(X[d], X[d], s2); }
  const float mu = s * (1.f / DD);
  const float rs = rsqrtf(fmaf(-mu, mu, s2 * (1.f / DD)) + EPSF);

  float ka[8], va[8];
#pragma unroll
  for (int j = 0; j < 8; ++j) { ka[j] = 0.f; va[j] = 0.f; }
#pragma unroll
  for (int d = 0; d < DD; ++d) {
    const float xn = fmaf((X[d] - mu) * rs, lnw[d], lnb[d]);
    X[d] = xn;
#pragma unroll
    for (int j = 0; j < 8; ++j) {
      ka[j] = fmaf(xn, Wk[d * 8 + j], ka[j]);
      va[j] = fmaf(xn, Wv[d * 8 + j], va[j]);
    }
  }

  {
    float4* kp = (float4*)(kb + ((size_t)l * NN + n) * 8);
    float4* vp = (float4*)(vb + ((size_t)l * NN + n) * 8);
    kp[0] = make_float4(ka[0], ka[1], ka[2], ka[3]);
    kp[1] = make_float4(ka[4], ka[5], ka[6], ka[7]);
    vp[0] = make_float4(va[0], va[1], va[2], va[3]);
    vp[1] = make_float4(va[4], va[5], va[6], va[7]);
  }

  {
    const bool hi1 = (lane & 16) != 0;
#pragma unroll
    for (int k = 0; k < 32; ++k) {
      const float keep = hi1 ? X[k + 32] : X[k];
      const float send = hi1 ? X[k] : X[k + 32];
      X[k] = keep + __shfl_xor(send, 16);
    }
    const bool hi2 = (lane & 32) != 0;
#pragma unroll
    for (int k = 0; k < 16; ++k) {
      const float keep = hi2 ? X[k + 16] : X[k];
      const float send = hi2 ? X[k] : X[k + 16];
      X[k] = keep + __shfl_xor(send, 32);
    }
  }
  const int d0 = ((lane >> 4) & 1) * 32 + (lane >> 5) * 16;
#pragma unroll
  for (int k = 0; k < 16; ++k) xc[w][l_loc][d0 + k] = X[k];
  __syncthreads();

#pragma unroll
  for (int j = 0; j < 4; ++j) {
    const int c = t * 4 + j;
    const int ll = c >> 6, d = c & 63;
    const float sv = xc[0][ll][d] + xc[1][ll][d] + xc[2][ll][d] + xc[3][ll][d];
    xbarP[((size_t)(l0 + ll) * NCH + nc) * DD + d] = sv;
  }
}

// ---------------------------------------------------------------------------
// Kernel B: unchanged from R6 (writes obT[d][l]).
// ---------------------------------------------------------------------------
__global__ __launch_bounds__(512) void kB(
    const float* __restrict__ kb, const float* __restrict__ vb,
    const float* __restrict__ xbarP, const float* __restrict__ Wq,
    float* __restrict__ obT)
{
  __shared__ float xbL[DD];
  __shared__ float qs[DD];
  __shared__ float ks[NN * 9];
  __shared__ float vs[NN * 9];
  const int l = blockIdx.x;
  const int t = threadIdx.x;
  const int h = t >> 6;
  const int lane = t & 63;

  const float* kl = kb + (size_t)l * NN * 8;
  const float* vl = vb + (size_t)l * NN * 8;
#pragma unroll
  for (int i = 0; i < 8; ++i) {
    const int idx = i * 512 + t;
    const int n = idx >> 3, j = idx & 7;
    ks[n*9 + j] = kl[idx];
    vs[n*9 + j] = vl[idx];
  }
  if (t < DD) {
    float s = 0.f;
    for (int p = 0; p < NCH; ++p) s += xbarP[((size_t)l * NCH + p) * DD + t];
    xbL[t] = s * (1.f / NN);
  }
  __syncthreads();
  if (t < DD) {
    float acc = 0.f;
    for (int d = 0; d < DD; ++d) acc = fmaf(xbL[d], Wq[d*DD + t], acc);
    qs[t] = acc * 0.35355339059327373f;
  }
  __syncthreads();

  float sc[8];
  float m = -1e30f;
#pragma unroll
  for (int i = 0; i < 8; ++i) {
    const int n = i * 64 + lane;
    float s = 0.f;
#pragma unroll
    for (int d = 0; d < 8; ++d) s = fmaf(qs[h*8 + d], ks[n*9 + d], s);
    sc[i] = s;
    m = fmaxf(m, s);
  }
#pragma unroll
  for (int off = 32; off; off >>= 1) m = fmaxf(m, __shfl_xor(m, off));
  float ssum = 0.f;
#pragma unroll
  for (int i = 0; i < 8; ++i) { sc[i] = __expf(sc[i] - m); ssum += sc[i]; }
#pragma unroll
  for (int off = 32; off; off >>= 1) ssum += __shfl_xor(ssum, off);
  const float inv = 1.f / ssum;

  float oacc[8];
#pragma unroll
  for (int d = 0; d < 8; ++d) oacc[d] = 0.f;
#pragma unroll
  for (int i = 0; i < 8; ++i) {
    const int n = i * 64 + lane;
#pragma unroll
    for (int d = 0; d < 8; ++d) oacc[d] = fmaf(sc[i], vs[n*9 + d], oacc[d]);
  }
#pragma unroll
  for (int d = 0; d < 8; ++d) {
#pragma unroll
    for (int off = 32; off; off >>= 1) oacc[d] += __shfl_xor(oacc[d], off);
  }
  if (lane == 0) {
#pragma unroll
    for (int d = 0; d < 8; ++d)
      obT[(size_t)(h * 8 + d) * LL + l] = oacc[d] * inv;
  }
}

// ---------------------------------------------------------------------------
// Kernel C v4 (zero-barrier, cvt_pk, 2-term mv1 / 3-term mv2):
// 128 rows/block, 256 thr = 4 waves; thread owns half-row; wave-private LDS.
// XH: xn_h then t_h; XL: t_l only.
// ---------------------------------------------------------------------------
__global__ __launch_bounds__(256, 4) void kC(
    const float* __restrict__ msa, const float* __restrict__ lnw, const float* __restrict__ lnb,
    const unsigned* __restrict__ Bpk, const float* __restrict__ bg,
    const float* __restrict__ obT, const float* __restrict__ bout,
    float* __restrict__ out)
{
  __shared__ unsigned short XH[128 * 72];  // 18 KB
  __shared__ unsigned short XL[128 * 72];  // 18 KB (t_lo)
  const int t = threadIdx.x;
  const int lane = t & 63;
  const int w = t >> 6;
  const int rbase = 32 * w;
  const size_t R0 = (size_t)blockIdx.x * 128;
  const int row = t >> 1;     // local row 0..127
  const int half = t & 1;     // 32-elem half

  // ---- phase 1: load + paired LN + bf16-h (cvt_pk) -> XH ----
  {
    const float4* rp = (const float4*)(msa + (R0 + row) * DD + half * 32);
    float4 r4[8];
#pragma unroll
    for (int i = 0; i < 8; ++i) r4[i] = rp[i];
    float s = 0.f, s2 = 0.f;
#pragma unroll
    for (int i = 0; i < 8; ++i) {
      const float4 f = r4[i];
      s += (f.x + f.y) + (f.z + f.w);
      s2 = fmaf(f.x, f.x, s2); s2 = fmaf(f.y, f.y, s2);
      s2 = fmaf(f.z, f.z, s2); s2 = fmaf(f.w, f.w, s2);
    }
    s += __shfl_xor(s, 1);
    s2 += __shfl_xor(s2, 1);
    const float mu = s * (1.f / DD);
    const float rs = rsqrtf(fmaf(-mu, mu, s2 * (1.f / DD)) + EPSF);
    const float aa = rs, bb = -mu * rs;
#pragma unroll
    for (int i = 0; i < 8; ++i) {
      const int d = half * 32 + 4 * i;
      const float xn0 = fmaf(fmaf(r4[i].x, aa, bb), lnw[d+0], lnb[d+0]);
      const float xn1 = fmaf(fmaf(r4[i].y, aa, bb), lnw[d+1], lnb[d+1]);
      const float xn2 = fmaf(fmaf(r4[i].z, aa, bb), lnw[d+2], lnb[d+2]);
      const float xn3 = fmaf(fmaf(r4[i].w, aa, bb), lnw[d+3], lnb[d+3]);
      const unsigned p01 = cvt_pk_bf16(xn0, xn1);
      const unsigned p23 = cvt_pk_bf16(xn2, xn3);
      *(uint2*)&XH[row * 72 + d] = make_uint2(p01, p23);
    }
  }
  // no barrier: rows 32w..32w+31 written & read only by wave w

  const short8* Bp = (const short8*)Bpk;   // frag*64 + lane

  auto run_mv = [&](int mvsel, bool three, f32x4 acc[2][4]) {
    short8 ah[2][2], al[2][2];
#pragma unroll
    for (int rt = 0; rt < 2; ++rt) {
      const int ar = rbase + rt * 16 + (lane & 15);
      const int kg = (lane >> 4) * 8;
      ah[rt][0] = *(const short8*)&XH[ar * 72 + kg];
      ah[rt][1] = *(const short8*)&XH[ar * 72 + 32 + kg];
      if (three) {
        al[rt][0] = *(const short8*)&XL[ar * 72 + kg];
        al[rt][1] = *(const short8*)&XL[ar * 72 + 32 + kg];
      }
    }
#pragma unroll
    for (int ct = 0; ct < 4; ++ct) {
      const short8 bh0 = Bp[((mvsel * 2 + 0) * 8 + ct * 2 + 0) * 64 + lane];
      const short8 bh1 = Bp[((mvsel * 2 + 0) * 8 + ct * 2 + 1) * 64 + lane];
      const short8 bl0 = Bp[((mvsel * 2 + 1) * 8 + ct * 2 + 0) * 64 + lane];
      const short8 bl1 = Bp[((mvsel * 2 + 1) * 8 + ct * 2 + 1) * 64 + lane];
#pragma unroll
      for (int rt = 0; rt < 2; ++rt) {
        f32x4 c = acc[rt][ct];
        c = __builtin_amdgcn_mfma_f32_16x16x32_bf16(ah[rt][0], bh0, c, 0, 0, 0);
        c = __builtin_amdgcn_mfma_f32_16x16x32_bf16(ah[rt][1], bh1, c, 0, 0, 0);
        c = __builtin_amdgcn_mfma_f32_16x16x32_bf16(ah[rt][0], bl0, c, 0, 0, 0);
        c = __builtin_amdgcn_mfma_f32_16x16x32_bf16(ah[rt][1], bl1, c, 0, 0, 0);
        if (three) {
          c = __builtin_amdgcn_mfma_f32_16x16x32_bf16(al[rt][0], bh0, c, 0, 0, 0);
          c = __builtin_amdgcn_mfma_f32_16x16x32_bf16(al[rt][1], bh1, c, 0, 0, 0);
        }
        acc[rt][ct] = c;
      }
    }
  };

  f32x4 acc[2][4];
#pragma unroll
  for (int rt = 0; rt < 2; ++rt)
#pragma unroll
    for (int ct = 0; ct < 4; ++ct) acc[rt][ct] = f32x4{0.f, 0.f, 0.f, 0.f};
  run_mv(0, false, acc);   // mv1: gate pre-activation (2-term)

  // ---- sigmoid * o -> t, split via cvt_pk into XH (hi) / XL (lo) ----
#pragma unroll
  for (int rt = 0; rt < 2; ++rt) {
    const int rl0 = rbase + rt * 16 + ((lane >> 4) << 2);
    const int li0 = (int)((R0 + rl0) & (LL - 1));
#pragma unroll
    for (int ct = 0; ct < 4; ++ct) {
      const int col = ct * 16 + (lane & 15);
      const float4 ov = *(const float4*)&obT[(size_t)col * LL + li0];
      const float bgc = bg[col];
      const float p0 = acc[rt][ct][0] + bgc;
      const float p1 = acc[rt][ct][1] + bgc;
      const float p2 = acc[rt][ct][2] + bgc;
      const float p3 = acc[rt][ct][3] + bgc;
      const float tv0 = ov.x / (1.f + __expf(-p0));
      const float tv1 = ov.y / (1.f + __expf(-p1));
      const float tv2 = ov.z / (1.f + __expf(-p2));
      const float tv3 = ov.w / (1.f + __expf(-p3));
      const unsigned ph01 = cvt_pk_bf16(tv0, tv1);
      const unsigned ph23 = cvt_pk_bf16(tv2, tv3);
      const float h0 = __uint_as_float(ph01 << 16);
      const float h1 = __uint_as_float(ph01 & 0xFFFF0000u);
      const float h2 = __uint_as_float(ph23 << 16);
      const float h3 = __uint_as_float(ph23 & 0xFFFF0000u);
      const unsigned pl01 = cvt_pk_bf16(tv0 - h0, tv1 - h1);
      const unsigned pl23 = cvt_pk_bf16(tv2 - h2, tv3 - h3);
      XH[(rl0 + 0) * 72 + col] = (unsigned short)ph01;
      XH[(rl0 + 1) * 72 + col] = (unsigned short)(ph01 >> 16);
      XH[(rl0 + 2) * 72 + col] = (unsigned short)ph23;
      XH[(rl0 + 3) * 72 + col] = (unsigned short)(ph23 >> 16);
      XL[(rl0 + 0) * 72 + col] = (unsigned short)pl01;
      XL[(rl0 + 1) * 72 + col] = (unsigned short)(pl01 >> 16);
      XL[(rl0 + 2) * 72 + col] = (unsigned short)pl23;
      XL[(rl0 + 3) * 72 + col] = (unsigned short)(pl23 >> 16);
    }
  }
  // no barrier: wave-private rows

  // mv2: out = t @ Wout + bout (3-term)
#pragma unroll
  for (int rt = 0; rt < 2; ++rt)
#pragma unroll
    for (int ct = 0; ct < 4; ++ct) {
      const float bo = bout[ct * 16 + (lane & 15)];
      acc[rt][ct] = f32x4{bo, bo, bo, bo};
    }
  run_mv(1, true, acc);

#pragma unroll
  for (int rt = 0; rt < 2; ++rt) {
#pragma unroll
    for (int j = 0; j < 4; ++j) {
      const size_t rg = R0 + rbase + rt * 16 + ((lane >> 4) << 2) + j;
#pragma unroll
      for (int ct = 0; ct < 4; ++ct)
        out[rg * DD + ct * 16 + (lane & 15)] = acc[rt][ct][j];
    }
  }
}

// ---------------------------------------------------------------------------
extern "C" void kernel_launch(void* const* d_in, const int* in_sizes, int n_in,
                              void* d_out, int out_size, void* d_ws, size_t ws_size,
                              hipStream_t stream)
{
  const float* msa  = (const float*)d_in[0];
  const float* lnw  = (const float*)d_in[1];
  const float* lnb  = (const float*)d_in[2];
  const float* Wq   = (const float*)d_in[3];
  const float* Wk   = (const float*)d_in[4];
  const float* Wv   = (const float*)d_in[5];
  const float* Wg   = (const float*)d_in[6];
  const float* bg   = (const float*)d_in[7];
  const float* Wout = (const float*)d_in[8];
  const float* bout = (const float*)d_in[9];
  float* out = (float*)d_out;

  float* kb    = (float*)d_ws;                        // (L, N, 8) 16 MB
  float* vb    = kb + (size_t)LL * NN * 8;            // (L, N, 8) 16 MB
  float* xbarP = vb + (size_t)LL * NN * 8;            // (L, 32, 64) 8 MB
  float* obT   = xbarP + (size_t)LL * NCH * DD;       // (64, L) 256 KB
  unsigned* Bpk = (unsigned*)(obT + (size_t)DD * LL); // 32 KB packed weights

  kW<<<32, 256, 0, stream>>>(Wg, Wout, Bpk);
  kA<<<64 * NCH, 256, 0, stream>>>(msa, lnw, lnb, Wk, Wv, kb, vb, xbarP);
  kB<<<LL, 512, 0, stream>>>(kb, vb, xbarP, Wq, obT);
  kC<<<(NN * LL) / 128, 256, 0, stream>>>(msa, lnw, lnb, Bpk, bg, obT, bout, out);
}